// Round 6
// baseline (227.185 us; speedup 1.0000x reference)
//
#include <hip/hip_runtime.h>

#define BATCH 4
#define NPTS  4096
#define NQ    8192
#define KNN   20
#define RES   64
#define FDIM  6
#define BN    (BATCH * NPTS)       // 16384 points total

#define NSEG    8                  // candidate segments per batch
#define SEG     (NPTS / NSEG)      // 512 candidates per segment
#define PPB     256                // points per block (filter)
#define PGROUPS (NPTS / PPB)       // 16

#define CAP8 32                    // survivor capacity per (point, segment)
// r0 = cbrt(60 / (4096 * 4/3*pi)) : radius capturing ~60 expected neighbours interior
#define R0 0.15179f

// ---------------- ws layout ----------------
// [0, GRID_BYTES)   : si survivor idx lists (8.4MB, aliases grid region; consumed
//                     by select BEFORE the grid memset), then grid (B,64,64,64,6)
// [GRID_BYTES,+128K): cnt (NSEG*BN uchars), written unconditionally (no memset)
// feat (B*NPTS*6 floats = 384KB) lives in the FRONT OF d_out: written by select,
// read by rasterize, then fully overwritten by interp's final output.
#define GRID_ELEMS ((size_t)BATCH * RES * RES * RES * FDIM)
#define GRID_BYTES (GRID_ELEMS * sizeof(float))                   // 25,165,824

__device__ __forceinline__ float dist2s(float cx, float cy, float cz,
                                        float px, float py, float pz) {
    float dx = cx - px, dy = cy - py, dz = cz - pz;
    return __builtin_fmaf(dz, dz, __builtin_fmaf(dy, dy, dx * dx));
}

// Branchless insert of pre-sorted pair (lo<=hi) into ascending 20-reg list.
#define PAIR_INSERT(d, lo, hi)                                   \
    _Pragma("unroll")                                            \
    for (int s = 0; s < KNN; ++s) {                              \
        float a_ = d[s];                                         \
        float mn_ = fminf(fminf(a_, lo), hi);                    \
        float md_ = __builtin_amdgcn_fmed3f(a_, lo, hi);         \
        float mx_ = fmaxf(fmaxf(a_, lo), hi);                    \
        d[s] = mn_; lo = md_; hi = mx_;                          \
    }

#define SINGLE_INSERT(d, v)                                      \
    _Pragma("unroll")                                            \
    for (int s = 0; s < KNN; ++s) {                              \
        float a_ = d[s];                                         \
        d[s] = fminf(a_, v); v = fmaxf(a_, v);                   \
    }

// ---------------------------------------------------------------------------
// K1: radius filter, owner-writes. Block = 256 points x one 512-cand segment
// (LDS-staged). Each thread appends survivor INDICES to its own contiguous
// region si[(seg*BN + pt)*CAP8 ...] — no atomics, no cross-block line sharing.
// Count per (pt,seg) written unconditionally as uchar.
// ---------------------------------------------------------------------------
__global__ __launch_bounds__(PPB) void filter_kernel(const float* __restrict__ pts,
                                                     unsigned short* __restrict__ si,
                                                     unsigned char* __restrict__ cnt) {
    const int bx  = blockIdx.x;
    const int seg = bx % NSEG;
    const int pg  = (bx / NSEG) % PGROUPS;
    const int b   = bx / (NSEG * PGROUPS);
    const int tid = threadIdx.x;

    __shared__ float4 shc[SEG];                 // 8 KB
    {
        const float* src = pts + ((size_t)b * NPTS + (size_t)seg * SEG) * 3;
        for (int i = tid; i < SEG; i += PPB)
            shc[i] = make_float4(src[i * 3 + 0], src[i * 3 + 1], src[i * 3 + 2], 0.f);
    }
    __syncthreads();

    const int pi = pg * PPB + tid;
    const int pt = b * NPTS + pi;
    const float* pp = pts + (size_t)pt * 3;
    const float px = pp[0], py = pp[1], pz = pp[2];

    // tau(p): radius capturing ~70 expected candidates, boundary-corrected
    // via box-clip fraction, 2 fixed-point iterations + 5% safety.
    float r = R0;
    #pragma unroll
    for (int it = 0; it < 2; ++it) {
        float ex = fminf(px + r, 1.f) - fmaxf(px - r, 0.f);
        float ey = fminf(py + r, 1.f) - fmaxf(py - r, 0.f);
        float ez = fminf(pz + r, 1.f) - fmaxf(pz - r, 0.f);
        float frac = (ex * ey * ez) / (8.f * r * r * r);
        r = R0 * __powf(frac, -1.f / 3.f);
    }
    r *= 1.05f;
    const float tau = r * r;

    const int base = seg * SEG;
    unsigned short* my = si + ((size_t)seg * BN + pt) * CAP8;
    int count = 0;

    #pragma unroll 4
    for (int j = 0; j < SEG; ++j) {
        float4 c = shc[j];
        float d2 = dist2s(c.x, c.y, c.z, px, py, pz);
        if (d2 <= tau) {
            if (count < CAP8) my[count] = (unsigned short)(base + j);
            ++count;
        }
    }
    cnt[(size_t)seg * BN + pt] = (unsigned char)(count > 255 ? 255 : count);
}

// ---------------------------------------------------------------------------
// K2: per point — recompute d2 for survivors (bit-identical fmaf), threshold-
// gated insert chain -> exact 20th dist t, then masked coord-max -> feature.
// Exact full-scan fallback if any seg overflowed or total<20 (never expected).
// ---------------------------------------------------------------------------
__global__ __launch_bounds__(64) void select_kernel(const float* __restrict__ pts,
                                                    const unsigned short* __restrict__ si,
                                                    const unsigned char* __restrict__ cnt,
                                                    float* __restrict__ feat) {
    const int pt = blockIdx.x * 64 + threadIdx.x;        // 0 .. BN-1
    const int b  = pt / NPTS;
    const float* pp = pts + (size_t)pt * 3;
    const float px = pp[0], py = pp[1], pz = pp[2];
    const float* pb = pts + (size_t)b * NPTS * 3;

    int n[NSEG];
    int total = 0;
    bool ok = true;
    #pragma unroll
    for (int s = 0; s < NSEG; ++s) {
        n[s] = cnt[(size_t)s * BN + pt];
        ok = ok && (n[s] <= CAP8);
        total += n[s];
    }

    float d[KNN];
    #pragma unroll
    for (int s = 0; s < KNN; ++s) d[s] = 3.4e38f;

    float gx = -3.4e38f, gy = -3.4e38f, gz = -3.4e38f;

    if (ok && total >= KNN) {
        #pragma unroll
        for (int s = 0; s < NSEG; ++s) {
            const unsigned short* my = si + ((size_t)s * BN + pt) * CAP8;
            const int ns = n[s];
            int k = 0;
            for (; k + 2 <= ns; k += 2) {
                int j0 = my[k], j1 = my[k + 1];
                const float* c0 = pb + j0 * 3;
                const float* c1 = pb + j1 * 3;
                float da = dist2s(c0[0], c0[1], c0[2], px, py, pz);
                float db = dist2s(c1[0], c1[1], c1[2], px, py, pz);
                float lo = fminf(da, db), hi = fmaxf(da, db);
                if (lo < d[KNN - 1]) {            // exact: pair >= max is a no-op
                    PAIR_INSERT(d, lo, hi)
                } else { (void)hi; }
            }
            if (k < ns) {
                int j = my[k];
                const float* c = pb + j * 3;
                float v = dist2s(c[0], c[1], c[2], px, py, pz);
                if (v < d[KNN - 1]) {
                    SINGLE_INSERT(d, v)
                }
            }
        }
        const float t = d[KNN - 1];
        #pragma unroll
        for (int s = 0; s < NSEG; ++s) {
            const unsigned short* my = si + ((size_t)s * BN + pt) * CAP8;
            const int ns = n[s];
            for (int k = 0; k < ns; ++k) {
                int j = my[k];
                const float* c = pb + j * 3;
                float d2 = dist2s(c[0], c[1], c[2], px, py, pz);
                if (d2 <= t) {
                    gx = fmaxf(gx, c[0]); gy = fmaxf(gy, c[1]); gz = fmaxf(gz, c[2]);
                }
            }
        }
    } else {
        // exact fallback: full scan (guaranteed correct, expected never)
        for (int j = 0; j < NPTS; j += 2) {
            const float* c0 = pb + j * 3;
            float da = dist2s(c0[0], c0[1], c0[2], px, py, pz);
            float db = dist2s(c0[3], c0[4], c0[5], px, py, pz);
            float lo = fminf(da, db), hi = fmaxf(da, db);
            PAIR_INSERT(d, lo, hi)
        }
        const float t = d[KNN - 1];
        for (int j = 0; j < NPTS; ++j) {
            const float* c = pb + j * 3;
            float d2 = dist2s(c[0], c[1], c[2], px, py, pz);
            if (d2 <= t) {
                gx = fmaxf(gx, c[0]); gy = fmaxf(gy, c[1]); gz = fmaxf(gz, c[2]);
            }
        }
    }

    float* f = feat + (size_t)pt * FDIM;
    f[0] = gx - px; f[1] = gy - py; f[2] = gz - pz;
    f[3] = px; f[4] = py; f[5] = pz;
}

// ---------------------------------------------------------------------------
// Trilinear corner setup, faithful to reference _corners().
// ---------------------------------------------------------------------------
__device__ __forceinline__ void corner_setup(float px, float py, float pz,
                                             int i0[3], int i1[3],
                                             float w0[3], float w1[3]) {
    float p[3] = {px, py, pz};
    #pragma unroll
    for (int d = 0; d < 3; ++d) {
        float f  = p[d] * 64.0f;
        float fl = floorf(f);
        i0[d] = (int)fl;
        i1[d] = ((int)ceilf(f)) & (RES - 1);
        float x0 = fl / 64.0f;
        float x1 = (fl + 1.0f) / 64.0f;
        w0[d] = fabsf(p[d] - x1) * 64.0f;   // corner bit == 0
        w1[d] = fabsf(p[d] - x0) * 64.0f;   // corner bit == 1
    }
}

// ---------------------------------------------------------------------------
// B: trilinear scatter-add of feat onto grid.
// ---------------------------------------------------------------------------
__global__ __launch_bounds__(256) void rasterize_kernel(const float* __restrict__ pts,
                                                        const float* __restrict__ feat,
                                                        float* __restrict__ grid) {
    int gid = blockIdx.x * 256 + threadIdx.x;            // 0 .. BN-1
    if (gid >= BN) return;
    int b = gid / NPTS;

    const float* p = pts + (size_t)gid * 3;
    float px = p[0], py = p[1], pz = p[2];

    float fv[FDIM];
    const float* f = feat + (size_t)gid * FDIM;
    #pragma unroll
    for (int c = 0; c < FDIM; ++c) fv[c] = f[c];

    int i0[3], i1[3];
    float w0[3], w1[3];
    corner_setup(px, py, pz, i0, i1, w0, w1);

    float* gb = grid + (size_t)b * RES * RES * RES * FDIM;
    #pragma unroll
    for (int c = 0; c < 8; ++c) {
        int bx = (c >> 2) & 1, by = (c >> 1) & 1, bz = c & 1;
        int ix = bx ? i1[0] : i0[0];
        int iy = by ? i1[1] : i0[1];
        int iz = bz ? i1[2] : i0[2];
        float w = (bx ? w1[0] : w0[0]) * (by ? w1[1] : w0[1]) * (bz ? w1[2] : w0[2]);
        size_t basei = ((size_t)(ix * RES + iy) * RES + iz) * FDIM;
        #pragma unroll
        for (int ch = 0; ch < FDIM; ++ch)
            atomicAdd(&gb[basei + ch], w * fv[ch]);
    }
}

// ---------------------------------------------------------------------------
// C: trilinear gather at query points.
// ---------------------------------------------------------------------------
__global__ __launch_bounds__(256) void interp_kernel(const float* __restrict__ query,
                                                     const float* __restrict__ grid,
                                                     float* __restrict__ out) {
    int gid = blockIdx.x * 256 + threadIdx.x;            // 0 .. B*NQ-1
    if (gid >= BATCH * NQ) return;
    int b = gid / NQ;

    const float* q = query + (size_t)gid * 3;
    float qx = q[0], qy = q[1], qz = q[2];

    int i0[3], i1[3];
    float w0[3], w1[3];
    corner_setup(qx, qy, qz, i0, i1, w0, w1);

    float acc[FDIM];
    #pragma unroll
    for (int ch = 0; ch < FDIM; ++ch) acc[ch] = 0.0f;

    const float* gb = grid + (size_t)b * RES * RES * RES * FDIM;
    #pragma unroll
    for (int c = 0; c < 8; ++c) {
        int bx = (c >> 2) & 1, by = (c >> 1) & 1, bz = c & 1;
        int ix = bx ? i1[0] : i0[0];
        int iy = by ? i1[1] : i0[1];
        int iz = bz ? i1[2] : i0[2];
        float w = (bx ? w1[0] : w0[0]) * (by ? w1[1] : w0[1]) * (bz ? w1[2] : w0[2]);
        const float2* g = (const float2*)(gb + ((size_t)(ix * RES + iy) * RES + iz) * FDIM);
        float2 g0 = g[0], g1 = g[1], g2 = g[2];
        acc[0] += w * g0.x; acc[1] += w * g0.y;
        acc[2] += w * g1.x; acc[3] += w * g1.y;
        acc[4] += w * g2.x; acc[5] += w * g2.y;
    }

    float* o = out + (size_t)gid * FDIM;
    #pragma unroll
    for (int ch = 0; ch < FDIM; ++ch) o[ch] = acc[ch];
}

// ---------------------------------------------------------------------------
extern "C" void kernel_launch(void* const* d_in, const int* in_sizes, int n_in,
                              void* d_out, int out_size, void* d_ws, size_t ws_size,
                              hipStream_t stream) {
    const float* pts   = (const float*)d_in[0];   // (4, 4096, 3)
    const float* query = (const float*)d_in[1];   // (4, 8192, 3)
    float* out = (float*)d_out;                   // (4, 8192, 6)

    unsigned short* si   = (unsigned short*)d_ws;          // 8.4MB, aliases grid
    float*          grid = (float*)d_ws;
    unsigned char*  cnt  = (unsigned char*)((char*)d_ws + GRID_BYTES);  // 128KB
    float*          feat = (float*)d_out;  // front 384KB of d_out; overwritten by interp

    filter_kernel<<<BATCH * PGROUPS * NSEG, PPB, 0, stream>>>(pts, si, cnt);
    select_kernel<<<BN / 64, 64, 0, stream>>>(pts, si, cnt, feat);

    hipMemsetAsync(grid, 0, GRID_BYTES, stream);   // after select consumed si alias

    rasterize_kernel<<<(BN + 255) / 256, 256, 0, stream>>>(pts, feat, grid);
    interp_kernel<<<(BATCH * NQ + 255) / 256, 256, 0, stream>>>(query, grid, out);
}